// Round 2
// baseline (267.268 us; speedup 1.0000x reference)
//
#include <hip/hip_runtime.h>
#include <hip/hip_bf16.h>

#define T_TOK 8192
#define DH    1024
#define NE    8
#define TK    4

typedef unsigned short u16;
typedef __bf16 bf16x8 __attribute__((ext_vector_type(8)));
typedef float  f32x4  __attribute__((ext_vector_type(4)));

__device__ __forceinline__ u16 f2b(float f) {
    union { float f; unsigned u; } v; v.f = f;
    unsigned u = v.u;
    u += 0x7FFFu + ((u >> 16) & 1u);   // round-to-nearest-even
    return (u16)(u >> 16);
}
__device__ __forceinline__ float b2f(u16 h) {
    union { unsigned u; float f; } v; v.u = ((unsigned)h) << 16;
    return v.f;
}
// async global->LDS, 16B per lane; LDS dest = wave-uniform base + lane*16 (linear!)
__device__ __forceinline__ void glds16(const u16* g, u16* l) {
    __builtin_amdgcn_global_load_lds((const __attribute__((address_space(1))) void*)g,
                                     (__attribute__((address_space(3))) void*)l, 16, 0, 0);
}

#define FENCE() asm volatile("" ::: "memory")
#define SBAR()  do { FENCE(); __builtin_amdgcn_s_barrier(); FENCE(); } while (0)
// rule 18: hipcc can hoist reg-only MFMA past an inline-asm lgkmcnt; fence with sched_barrier(0)
#define WAITLGKM0() do { asm volatile("s_waitcnt lgkmcnt(0)" ::: "memory"); \
                         __builtin_amdgcn_sched_barrier(0); } while (0)

// ---------------- cast W -> bf16, transposed to [e][f][d]; 64x64 tile, vectorized ----------------
__global__ __launch_bounds__(256) void cast_w_kernel(const float* __restrict__ W,
                                                     u16* __restrict__ wbt) {
    __shared__ float tile[64][65];
    const int e  = blockIdx.z;
    const int d0 = blockIdx.y * 64;
    const int f0 = blockIdx.x * 64;
    const int r  = threadIdx.x >> 4;          // 0..15
    const int c4 = (threadIdx.x & 15) * 4;    // 0,4,...,60
    const float* src = W + ((size_t)e << 20) + (size_t)d0 * DH + f0;
    #pragma unroll
    for (int i = 0; i < 4; i++) {
        const int row = i * 16 + r;
        const float4 v = *(const float4*)(src + (size_t)row * DH + c4);
        tile[row][c4]     = v.x;
        tile[row][c4 + 1] = v.y;
        tile[row][c4 + 2] = v.z;
        tile[row][c4 + 3] = v.w;
    }
    __syncthreads();
    u16* dst = wbt + ((size_t)e << 20) + (size_t)f0 * DH + d0;
    #pragma unroll
    for (int i = 0; i < 4; i++) {
        const int orow = i * 16 + r;          // f-index within tile
        ushort4 o;
        o.x = f2b(tile[c4][orow]);
        o.y = f2b(tile[c4 + 1][orow]);
        o.z = f2b(tile[c4 + 2][orow]);
        o.w = f2b(tile[c4 + 3][orow]);
        *(ushort4*)(dst + (size_t)orow * DH + c4) = o;
    }
}

// ---------------- router: logits + softmax + top4 + buckets, fused x->bf16 cast ----------------
__global__ __launch_bounds__(512) void router_kernel(
    const float* __restrict__ x, const float* __restrict__ Wg, const float* __restrict__ bg,
    u16* __restrict__ xb,
    int* __restrict__ bucket_tok, float* __restrict__ bucket_w,
    int* __restrict__ tk_e, float* __restrict__ tk_w,
    int* __restrict__ cnt, float* __restrict__ probsum)
{
    __shared__ int   lcnt[NE];
    __shared__ float lprob[NE];
    __shared__ int   gbase[NE];
    const int tid = threadIdx.x;
    const int wv = tid >> 6, lane = tid & 63;
    const int t = blockIdx.x * 8 + wv;
    if (tid < NE) { lcnt[tid] = 0; lprob[tid] = 0.f; }
    __syncthreads();

    float a[NE] = {};
    {
        const float* xr = x + (size_t)t * DH;
        u16* xbr = xb + (size_t)t * DH;
        #pragma unroll
        for (int it = 0; it < 4; it++) {
            const int d = it * 256 + lane * 4;
            const float4 v = *(const float4*)(xr + d);
            ushort4 o;
            o.x = f2b(v.x); o.y = f2b(v.y); o.z = f2b(v.z); o.w = f2b(v.w);
            *(ushort4*)(xbr + d) = o;
            const float* wr = Wg + d * NE;
            #pragma unroll
            for (int e = 0; e < NE; e++)
                a[e] += v.x * wr[e] + v.y * wr[NE + e] + v.z * wr[2 * NE + e] + v.w * wr[3 * NE + e];
        }
    }
    #pragma unroll
    for (int e = 0; e < NE; e++) {
        float v = a[e];
        #pragma unroll
        for (int off = 32; off > 0; off >>= 1) v += __shfl_down(v, off);
        a[e] = v;
    }

    int idx4[TK]; float w4[TK]; int off4[TK];
    if (lane == 0) {
        float logits[NE], probs[NE];
        float mx = -1e30f;
        #pragma unroll
        for (int e = 0; e < NE; e++) { logits[e] = a[e] + bg[e]; mx = fmaxf(mx, logits[e]); }
        float Z = 0.f;
        #pragma unroll
        for (int e = 0; e < NE; e++) { probs[e] = expf(logits[e] - mx); Z += probs[e]; }
        const float rZ = 1.f / Z;
        #pragma unroll
        for (int e = 0; e < NE; e++) probs[e] *= rZ;

        float rem2[NE];
        #pragma unroll
        for (int e = 0; e < NE; e++) rem2[e] = probs[e];
        float s4 = 0.f;
        #pragma unroll
        for (int k = 0; k < TK; k++) {   // strict > scan from 0 == jax tie-break (lowest idx)
            int best = 0; float bv = rem2[0];
            #pragma unroll
            for (int e = 1; e < NE; e++) if (rem2[e] > bv) { bv = rem2[e]; best = e; }
            idx4[k] = best; w4[k] = bv; s4 += bv; rem2[best] = -1e30f;
        }
        const float rs = 1.f / (s4 + 1e-6f);
        #pragma unroll
        for (int k = 0; k < TK; k++) {
            w4[k] *= rs;
            tk_e[t * TK + k] = idx4[k];
            tk_w[t * TK + k] = w4[k];
            off4[k] = atomicAdd(&lcnt[idx4[k]], 1);
        }
        #pragma unroll
        for (int e = 0; e < NE; e++) atomicAdd(&lprob[e], probs[e]);
    }
    __syncthreads();
    if (tid < NE) {
        gbase[tid] = atomicAdd(&cnt[tid], lcnt[tid]);
        atomicAdd(&probsum[tid], lprob[tid]);
    }
    __syncthreads();
    if (lane == 0) {
        #pragma unroll
        for (int k = 0; k < TK; k++) {
            const int e = idx4[k];
            const int slot = gbase[e] + off4[k];
            bucket_tok[e * T_TOK + slot] = (t << 2) | k;
            bucket_w[e * T_TOK + slot]   = w4[k];
        }
    }
}

// ---------------- grouped gather GEMM, 256x256 / BK=64 / 8-wave / 4-phase-per-K-tile ----------------
// R2 structural port of the m201 8-phase template:
//  - BM=BN=256, BK=64, 512 thr (waves 2Mx4N), per-wave C = 128x64 (acc f32x4[8][4]).
//  - LDS 130KB: As/Bs double-buffered [2][256][64] u16, XOR-swizzled (T2): within each
//    128B row, 16B slot s holds global slot s ^ (row&7). glds16 writes linearly (rule 21),
//    so the *global source* address is pre-swizzled; ds_read applies the same XOR.
//    Read check: lanes 0-15 (rows r..r+15) land on bank-groups ((fr&7)^(col/16))*4 -> 2-way (free).
//  - Schedule per K-tile (T3+T4): P1{read afL+bfL(12); BAR; lgkm0; 16 MFMA; BAR}
//    P2{read bfH(4); ...} P3{read afH(8); ...} P4{stage kt+2; 16 MFMA; vmcnt(8); BAR}.
//    vmcnt(8) leaves tile kt+2's 8 loads in flight -> tile kt+1 resident. Never 0 mid-loop.
//  - T5 setprio(1) around each 16-MFMA cluster (pays only in phase-split schedules).
//  - Persistent grid: 256 blocks stride a 1024-entry m-major virtual tile space
//    (vt = mb*32 + e*4 + nb); with M_e ~ 4096 each block gets ~2 active tiles -> balanced.
__global__ __launch_bounds__(512, 2) void moe_gemm_kernel(
    const u16* __restrict__ xb, const u16* __restrict__ wbt,
    const int* __restrict__ bucket_tok, const float* __restrict__ bucket_w,
    const int* __restrict__ cnt, u16* __restrict__ y)
{
    __shared__ u16 As[2][256 * 64];   // 64 KB
    __shared__ u16 Bs[2][256 * 64];   // 64 KB
    __shared__ int   s_tok[256];
    __shared__ float s_w[256];

    const int tid  = threadIdx.x;
    const int lane = tid & 63;
    const int wid  = tid >> 6;            // 0..7
    const int wr   = wid >> 2;            // 0..1 (M)
    const int wc   = wid & 3;             // 0..3 (N)
    const int fr   = lane & 15;
    const int fq   = (lane >> 4) * 8;
    const int swz  = (fr & 7) << 3;       // u16-index XOR for frag reads
    const int gsw  = ((lane & 7) ^ (lane >> 3)) * 8;  // pre-swizzled global u16 col for staging
    const int crow = lane >> 3;           // row within 8-row chunk

    for (int vt = blockIdx.x; vt < 1024; vt += 256) {
        const int mb = vt >> 5;
        const int e  = (vt >> 2) & 7;
        const int nb = vt & 3;
        const int M  = cnt[e];
        const int m0 = mb << 8;
        if (m0 >= M) continue;
        const int n0 = nb << 8;

        __syncthreads();                   // s_tok/s_w reuse across virtual tiles
        if (tid < 256) {
            const int slot = m0 + tid;
            if (slot < M) {
                s_tok[tid] = bucket_tok[e * T_TOK + slot];
                s_w[tid]   = bucket_w[e * T_TOK + slot];
            } else { s_tok[tid] = -1; s_w[tid] = 0.f; }
        }
        __syncthreads();

        // staging pointers: wave wid owns chunks wid*4+q (8 rows x 128B each) of As and Bs
        const u16* gA[4]; const u16* gB[4];
        #pragma unroll
        for (int q = 0; q < 4; q++) {
            const int row = wid * 32 + q * 8 + crow;
            const int tok = s_tok[row];
            gA[q] = xb + (size_t)(tok >= 0 ? (tok >> 2) : 0) * DH + gsw;
            gB[q] = wbt + ((size_t)e << 20) + (size_t)(n0 + row) * DH + gsw;
        }

        f32x4 acc[8][4] = {};

        auto STAGE = [&](int kt) {
            const int p  = kt & 1;
            const int ko = kt * 64;
            #pragma unroll
            for (int q = 0; q < 4; q++)
                glds16(gA[q] + ko, &As[p][(wid * 4 + q) * 512]);
            #pragma unroll
            for (int q = 0; q < 4; q++)
                glds16(gB[q] + ko, &Bs[p][(wid * 4 + q) * 512]);
        };

        STAGE(0); STAGE(1);                               // 16 in flight
        asm volatile("s_waitcnt vmcnt(8)" ::: "memory");  // tile 0 resident
        SBAR();

        const int arow = (wr * 128 + fr) * 64;    // u16 base of this lane's A frag rows
        const int brow = (wc * 64  + fr) * 64;
        const int c0 = fq ^ swz;                  // k-half 0 column (u16)
        const int c1 = (32 + fq) ^ swz;           // k-half 1 column

        bf16x8 afL[4][2], afH[4][2], bfL[2][2], bfH[2][2];

        for (int kt = 0; kt < 16; ++kt) {
            const int p = kt & 1;
            const u16* Ap = &As[p][0];
            const u16* Bp = &Bs[p][0];

            // ---- P1: read afL(8) + bfL(4); MFMA mi0-3 x nj0-1 ----
            #pragma unroll
            for (int mi = 0; mi < 4; mi++) {
                afL[mi][0] = *(const bf16x8*)&Ap[arow + mi * 1024 + c0];
                afL[mi][1] = *(const bf16x8*)&Ap[arow + mi * 1024 + c1];
            }
            #pragma unroll
            for (int nj = 0; nj < 2; nj++) {
                bfL[nj][0] = *(const bf16x8*)&Bp[brow + nj * 1024 + c0];
                bfL[nj][1] = *(const bf16x8*)&Bp[brow + nj * 1024 + c1];
            }
            SBAR(); WAITLGKM0();
            __builtin_amdgcn_s_setprio(1);
            #pragma unroll
            for (int mi = 0; mi < 4; mi++)
                #pragma unroll
                for (int nj = 0; nj < 2; nj++) {
                    acc[mi][nj] = __builtin_amdgcn_mfma_f32_16x16x32_bf16(afL[mi][0], bfL[nj][0], acc[mi][nj], 0, 0, 0);
                    acc[mi][nj] = __builtin_amdgcn_mfma_f32_16x16x32_bf16(afL[mi][1], bfL[nj][1], acc[mi][nj], 0, 0, 0);
                }
            __builtin_amdgcn_s_setprio(0);
            SBAR();

            // ---- P2: read bfH(4); MFMA mi0-3 x nj2-3 ----
            #pragma unroll
            for (int nj = 0; nj < 2; nj++) {
                bfH[nj][0] = *(const bf16x8*)&Bp[brow + (nj + 2) * 1024 + c0];
                bfH[nj][1] = *(const bf16x8*)&Bp[brow + (nj + 2) * 1024 + c1];
            }
            SBAR(); WAITLGKM0();
            __builtin_amdgcn_s_setprio(1);
            #pragma unroll
            for (int mi = 0; mi < 4; mi++)
                #pragma unroll
                for (int nj = 0; nj < 2; nj++) {
                    acc[mi][nj + 2] = __builtin_amdgcn_mfma_f32_16x16x32_bf16(afL[mi][0], bfH[nj][0], acc[mi][nj + 2], 0, 0, 0);
                    acc[mi][nj + 2] = __builtin_amdgcn_mfma_f32_16x16x32_bf16(afL[mi][1], bfH[nj][1], acc[mi][nj + 2], 0, 0, 0);
                }
            __builtin_amdgcn_s_setprio(0);
            SBAR();

            // ---- P3: read afH(8); MFMA mi4-7 x nj2-3 ----
            #pragma unroll
            for (int mi = 0; mi < 4; mi++) {
                afH[mi][0] = *(const bf16x8*)&Ap[arow + (mi + 4) * 1024 + c0];
                afH[mi][1] = *(const bf16x8*)&Ap[arow + (mi + 4) * 1024 + c1];
            }
            SBAR(); WAITLGKM0();
            __builtin_amdgcn_s_setprio(1);
            #pragma unroll
            for (int mi = 0; mi < 4; mi++)
                #pragma unroll
                for (int nj = 0; nj < 2; nj++) {
                    acc[mi + 4][nj + 2] = __builtin_amdgcn_mfma_f32_16x16x32_bf16(afH[mi][0], bfH[nj][0], acc[mi + 4][nj + 2], 0, 0, 0);
                    acc[mi + 4][nj + 2] = __builtin_amdgcn_mfma_f32_16x16x32_bf16(afH[mi][1], bfH[nj][1], acc[mi + 4][nj + 2], 0, 0, 0);
                }
            __builtin_amdgcn_s_setprio(0);
            SBAR();   // all reads of buf p retired in all waves -> safe to restage it

            // ---- P4: stage kt+2 -> buf p; MFMA mi4-7 x nj0-1 (regs only) ----
            if (kt < 14) STAGE(kt + 2);
            __builtin_amdgcn_s_setprio(1);
            #pragma unroll
            for (int mi = 0; mi < 4; mi++)
                #pragma unroll
                for (int nj = 0; nj < 2; nj++) {
                    acc[mi + 4][nj] = __builtin_amdgcn_mfma_f32_16x16x32_bf16(afH[mi][0], bfL[nj][0], acc[mi + 4][nj], 0, 0, 0);
                    acc[mi + 4][nj] = __builtin_amdgcn_mfma_f32_16x16x32_bf16(afH[mi][1], bfL[nj][1], acc[mi + 4][nj], 0, 0, 0);
                }
            __builtin_amdgcn_s_setprio(0);
            if (kt < 14)       asm volatile("s_waitcnt vmcnt(8)" ::: "memory");  // tile kt+1 resident
            else if (kt == 14) asm volatile("s_waitcnt vmcnt(0)" ::: "memory");  // drain for last tile
            SBAR();
        }

        // C/D layout: col = lane&15, row = (lane>>4)*4 + r
        const int cl = lane & 15;
        const int rb = (lane >> 4) * 4;
        #pragma unroll
        for (int mi = 0; mi < 8; mi++) {
            #pragma unroll
            for (int r = 0; r < 4; r++) {
                const int srow = wr * 128 + mi * 16 + rb + r;
                const int tok = s_tok[srow];
                if (tok < 0) continue;
                const float w = s_w[srow];
                u16* yr = y + (size_t)tok * DH + (n0 + wc * 64 + cl);
                #pragma unroll
                for (int nj = 0; nj < 4; nj++)
                    yr[nj * 16] = f2b(acc[mi][nj][r] * w);
            }
        }
    }
}

// ---------------- combine: out[t] = sum_k y[t*4+k] + sum_k w_k*b[e_k]; block 0 does aux ----------------
__global__ __launch_bounds__(256) void combine_kernel(
    const u16* __restrict__ y, const int* __restrict__ tk_e, const float* __restrict__ tk_w,
    const float* __restrict__ bexp,
    const int* __restrict__ cnt, const float* __restrict__ probsum,
    float* __restrict__ out, float* __restrict__ out_aux)
{
    const int t = blockIdx.x;
    const int c = threadIdx.x * 4;
    if (t == 0 && threadIdx.x == 0) {
        float s = 0.f;
        for (int e = 0; e < NE; e++) s += (float)cnt[e] * probsum[e];
        out_aux[0] = s * (float)NE / ((float)T_TOK * (float)T_TOK);
    }
    float o0 = 0.f, o1 = 0.f, o2 = 0.f, o3 = 0.f;
    #pragma unroll
    for (int k = 0; k < TK; k++) {
        const int e   = tk_e[t * TK + k];
        const float w = tk_w[t * TK + k];
        const ushort4 yv = *(const ushort4*)(y + ((size_t)(t * TK + k)) * DH + c);
        const float4  bv = *(const float4*)(bexp + (size_t)e * DH + c);
        o0 += b2f(yv.x) + w * bv.x;
        o1 += b2f(yv.y) + w * bv.y;
        o2 += b2f(yv.z) + w * bv.z;
        o3 += b2f(yv.w) + w * bv.w;
    }
    float4 ov = {o0, o1, o2, o3};
    *(float4*)(out + (size_t)t * DH + c) = ov;
}

extern "C" void kernel_launch(void* const* d_in, const int* in_sizes, int n_in,
                              void* d_out, int out_size, void* d_ws, size_t ws_size,
                              hipStream_t stream)
{
    const float* x  = (const float*)d_in[0];
    const float* Wg = (const float*)d_in[1];
    const float* bg = (const float*)d_in[2];
    const float* W  = (const float*)d_in[3];
    const float* b  = (const float*)d_in[4];
    float* out = (float*)d_out;

    char* ws = (char*)d_ws;
    u16*   xb         = (u16*)(ws);                    // 16,777,216 B
    u16*   wbt        = (u16*)(ws + 16777216);         // 16,777,216 B
    u16*   y          = (u16*)(ws + 33554432);         // 67,108,864 B
    int*   bucket_tok = (int*)(ws + 100663296);        //    262,144 B
    float* bucket_w   = (float*)(ws + 100925440);      //    262,144 B
    int*   tk_e       = (int*)(ws + 101187584);        //    131,072 B
    float* tk_w       = (float*)(ws + 101318656);      //    131,072 B
    int*   cnt        = (int*)(ws + 101449728);        //         32 B
    float* probsum    = (float*)(ws + 101449760);      //         32 B

    hipMemsetAsync(cnt, 0, 64, stream);  // cnt + probsum

    cast_w_kernel<<<dim3(16, 16, NE), 256, 0, stream>>>(W, wbt);
    router_kernel<<<1024, 512, 0, stream>>>(x, Wg, bg, xb, bucket_tok, bucket_w, tk_e, tk_w, cnt, probsum);
    moe_gemm_kernel<<<dim3(256), 512, 0, stream>>>(xb, wbt, bucket_tok, bucket_w, cnt, y);
    combine_kernel<<<8192, 256, 0, stream>>>(y, tk_e, tk_w, b, cnt, probsum, out, out + (size_t)T_TOK * DH);
}

// Round 3
// 256.381 us; speedup vs baseline: 1.0425x; 1.0425x over previous
//
#include <hip/hip_runtime.h>
#include <hip/hip_bf16.h>

#define T_TOK 8192
#define DH    1024
#define NE    8
#define TK    4

typedef unsigned short u16;
typedef __bf16 bf16x8 __attribute__((ext_vector_type(8)));
typedef float  f32x4  __attribute__((ext_vector_type(4)));

__device__ __forceinline__ u16 f2b(float f) {
    union { float f; unsigned u; } v; v.f = f;
    unsigned u = v.u;
    u += 0x7FFFu + ((u >> 16) & 1u);   // round-to-nearest-even
    return (u16)(u >> 16);
}
__device__ __forceinline__ float b2f(u16 h) {
    union { unsigned u; float f; } v; v.u = ((unsigned)h) << 16;
    return v.f;
}
// async global->LDS, 16B per lane; LDS dest = wave-uniform base + lane*16 (linear!)
__device__ __forceinline__ void glds16(const u16* g, u16* l) {
    __builtin_amdgcn_global_load_lds((const __attribute__((address_space(1))) void*)g,
                                     (__attribute__((address_space(3))) void*)l, 16, 0, 0);
}

#define FENCE() asm volatile("" ::: "memory")
#define SBAR()  do { FENCE(); __builtin_amdgcn_s_barrier(); FENCE(); } while (0)
// rule 18: hipcc can hoist reg-only MFMA past an inline-asm lgkmcnt; fence with sched_barrier(0)
#define WAITLGKM0() do { asm volatile("s_waitcnt lgkmcnt(0)" ::: "memory"); \
                         __builtin_amdgcn_sched_barrier(0); } while (0)

// ---------------- cast W -> bf16, transposed to [e][f][d]; 64x64 tile, vectorized ----------------
__global__ __launch_bounds__(256) void cast_w_kernel(const float* __restrict__ W,
                                                     u16* __restrict__ wbt) {
    __shared__ float tile[64][65];
    const int e  = blockIdx.z;
    const int d0 = blockIdx.y * 64;
    const int f0 = blockIdx.x * 64;
    const int r  = threadIdx.x >> 4;          // 0..15
    const int c4 = (threadIdx.x & 15) * 4;    // 0,4,...,60
    const float* src = W + ((size_t)e << 20) + (size_t)d0 * DH + f0;
    #pragma unroll
    for (int i = 0; i < 4; i++) {
        const int row = i * 16 + r;
        const float4 v = *(const float4*)(src + (size_t)row * DH + c4);
        tile[row][c4]     = v.x;
        tile[row][c4 + 1] = v.y;
        tile[row][c4 + 2] = v.z;
        tile[row][c4 + 3] = v.w;
    }
    __syncthreads();
    u16* dst = wbt + ((size_t)e << 20) + (size_t)f0 * DH + d0;
    #pragma unroll
    for (int i = 0; i < 4; i++) {
        const int orow = i * 16 + r;          // f-index within tile
        ushort4 o;
        o.x = f2b(tile[c4][orow]);
        o.y = f2b(tile[c4 + 1][orow]);
        o.z = f2b(tile[c4 + 2][orow]);
        o.w = f2b(tile[c4 + 3][orow]);
        *(ushort4*)(dst + (size_t)orow * DH + c4) = o;
    }
}

// ---------------- router: logits + softmax + top4 + buckets, fused x->bf16 cast ----------------
// R3: Wg reads vectorized (8 float4 per iter vs 32 scalars); accumulation order kept
// bit-identical to previous rounds (a[e] += x0*W[d][e] + x1*W[d+1][e] + ...) to avoid
// flipping near-tie top-k selections.
__global__ __launch_bounds__(512) void router_kernel(
    const float* __restrict__ x, const float* __restrict__ Wg, const float* __restrict__ bg,
    u16* __restrict__ xb,
    int* __restrict__ bucket_tok, float* __restrict__ bucket_w,
    int* __restrict__ tk_e, float* __restrict__ tk_w,
    int* __restrict__ cnt, float* __restrict__ probsum)
{
    __shared__ int   lcnt[NE];
    __shared__ float lprob[NE];
    __shared__ int   gbase[NE];
    const int tid = threadIdx.x;
    const int wv = tid >> 6, lane = tid & 63;
    const int t = blockIdx.x * 8 + wv;
    if (tid < NE) { lcnt[tid] = 0; lprob[tid] = 0.f; }
    __syncthreads();

    float a[NE] = {};
    {
        const float* xr = x + (size_t)t * DH;
        u16* xbr = xb + (size_t)t * DH;
        const float4* wg = (const float4*)Wg;   // row d -> wg[2d] (e0..3), wg[2d+1] (e4..7)
        #pragma unroll
        for (int it = 0; it < 4; it++) {
            const int d = it * 256 + lane * 4;
            const float4 v = *(const float4*)(xr + d);
            ushort4 o;
            o.x = f2b(v.x); o.y = f2b(v.y); o.z = f2b(v.z); o.w = f2b(v.w);
            *(ushort4*)(xbr + d) = o;
            const float4 w0l = wg[2 * (d + 0)], w0h = wg[2 * (d + 0) + 1];
            const float4 w1l = wg[2 * (d + 1)], w1h = wg[2 * (d + 1) + 1];
            const float4 w2l = wg[2 * (d + 2)], w2h = wg[2 * (d + 2) + 1];
            const float4 w3l = wg[2 * (d + 3)], w3h = wg[2 * (d + 3) + 1];
            a[0] += v.x * w0l.x + v.y * w1l.x + v.z * w2l.x + v.w * w3l.x;
            a[1] += v.x * w0l.y + v.y * w1l.y + v.z * w2l.y + v.w * w3l.y;
            a[2] += v.x * w0l.z + v.y * w1l.z + v.z * w2l.z + v.w * w3l.z;
            a[3] += v.x * w0l.w + v.y * w1l.w + v.z * w2l.w + v.w * w3l.w;
            a[4] += v.x * w0h.x + v.y * w1h.x + v.z * w2h.x + v.w * w3h.x;
            a[5] += v.x * w0h.y + v.y * w1h.y + v.z * w2h.y + v.w * w3h.y;
            a[6] += v.x * w0h.z + v.y * w1h.z + v.z * w2h.z + v.w * w3h.z;
            a[7] += v.x * w0h.w + v.y * w1h.w + v.z * w2h.w + v.w * w3h.w;
        }
    }
    #pragma unroll
    for (int e = 0; e < NE; e++) {
        float v = a[e];
        #pragma unroll
        for (int off = 32; off > 0; off >>= 1) v += __shfl_down(v, off);
        a[e] = v;
    }

    int idx4[TK]; float w4[TK]; int off4[TK];
    if (lane == 0) {
        float logits[NE], probs[NE];
        float mx = -1e30f;
        #pragma unroll
        for (int e = 0; e < NE; e++) { logits[e] = a[e] + bg[e]; mx = fmaxf(mx, logits[e]); }
        float Z = 0.f;
        #pragma unroll
        for (int e = 0; e < NE; e++) { probs[e] = expf(logits[e] - mx); Z += probs[e]; }
        const float rZ = 1.f / Z;
        #pragma unroll
        for (int e = 0; e < NE; e++) probs[e] *= rZ;

        float rem2[NE];
        #pragma unroll
        for (int e = 0; e < NE; e++) rem2[e] = probs[e];
        float s4 = 0.f;
        #pragma unroll
        for (int k = 0; k < TK; k++) {   // strict > scan from 0 == jax tie-break (lowest idx)
            int best = 0; float bv = rem2[0];
            #pragma unroll
            for (int e = 1; e < NE; e++) if (rem2[e] > bv) { bv = rem2[e]; best = e; }
            idx4[k] = best; w4[k] = bv; s4 += bv; rem2[best] = -1e30f;
        }
        const float rs = 1.f / (s4 + 1e-6f);
        #pragma unroll
        for (int k = 0; k < TK; k++) {
            w4[k] *= rs;
            tk_e[t * TK + k] = idx4[k];
            tk_w[t * TK + k] = w4[k];
            off4[k] = atomicAdd(&lcnt[idx4[k]], 1);
        }
        #pragma unroll
        for (int e = 0; e < NE; e++) atomicAdd(&lprob[e], probs[e]);
    }
    __syncthreads();
    if (tid < NE) {
        gbase[tid] = atomicAdd(&cnt[tid], lcnt[tid]);
        atomicAdd(&probsum[tid], lprob[tid]);
    }
    __syncthreads();
    if (lane == 0) {
        #pragma unroll
        for (int k = 0; k < TK; k++) {
            const int e = idx4[k];
            const int slot = gbase[e] + off4[k];
            bucket_tok[e * T_TOK + slot] = (t << 2) | k;
            bucket_w[e * T_TOK + slot]   = w4[k];
        }
    }
}

// ---------------- grouped gather GEMM, 256x256 / BK=64 / 8-wave / 4-phase-per-K-tile ----------------
// R3 = R2 with m201-faithful fine interleave (m196: coarse staging is -7..27%):
//  - Staging spread 2 glds16 per phase, half-granular WAR retirement:
//      A-L/B-L rows of buf p die at end-P1, B-H at end-P2, A-H at end-P3. So tile kt+2
//      stages into buf p progressively: A-L@P2, B-L@P3, B-H@P4; A-H@(P1 of kt+1).
//  - Counted wait once per K-tile: vmcnt(6) at P4 (= the 6 strictly-newer kt+2 parts
//      in flight -> tile kt+1 fully resident). m201's N=6 formula re-derived. Never 0 mid-loop.
//  - 12-read phase gets the template's optional s_waitcnt lgkmcnt(8) hint.
//  - T2 0-conflict XOR swizzle (verified R2: SQ_LDS_BANK_CONFLICT = 0) kept; T5 setprio kept.
//  - Grid: expert-per-XCD (e = bid&7, bid%8 -> XCD heuristic): wbt[e] (2MB) L2-resident per XCD,
//      same-XCD blocks share gathered A-panels. Balance unchanged (~2 active tiles/block).
__global__ __launch_bounds__(512, 2) void moe_gemm_kernel(
    const u16* __restrict__ xb, const u16* __restrict__ wbt,
    const int* __restrict__ bucket_tok, const float* __restrict__ bucket_w,
    const int* __restrict__ cnt, u16* __restrict__ y)
{
    __shared__ u16 As[2][256 * 64];   // 64 KB
    __shared__ u16 Bs[2][256 * 64];   // 64 KB
    __shared__ int   s_tok[256];
    __shared__ float s_w[256];

    const int tid  = threadIdx.x;
    const int lane = tid & 63;
    const int wid  = tid >> 6;            // 0..7
    const int wr   = wid >> 2;            // 0..1 (M)
    const int wc   = wid & 3;             // 0..3 (N)
    const int fr   = lane & 15;
    const int fq   = (lane >> 4) * 8;
    const int swz  = (fr & 7) << 3;       // u16-index XOR for frag reads
    const int gsw  = ((lane & 7) ^ (lane >> 3)) * 8;  // pre-swizzled global u16 col for staging
    const int crow = lane >> 3;           // row within 8-row chunk

    // chunk ownership (chunk = 8 rows x 128B, staged by one glds16):
    // A-L set {0-7,16-23}, A-H = +8; B-L set {(c&7)<4}, B-H = +4. 2 chunks per set per wave.
    const int ALb = 2 * wid + (wid >= 4 ? 8 : 0);
    const int AHb = ALb + 8;
    const int BLb = (wid >> 1) * 8 + (wid & 1) * 2;
    const int BHb = BLb + 4;

    const int e = blockIdx.x & 7;          // expert-per-XCD
    const int c = blockIdx.x >> 3;         // 0..31 within XCD
    const int M = cnt[e];

    for (int j = 0; j < 4; ++j) {
        const int idx = j * 32 + c;        // tile index within expert
        const int mb = idx >> 2;
        const int nb = idx & 3;
        const int m0 = mb << 8;
        if (m0 >= M) continue;
        const int n0 = nb << 8;

        __syncthreads();                   // s_tok/s_w reuse across virtual tiles
        if (tid < 256) {
            const int slot = m0 + tid;
            if (slot < M) {
                s_tok[tid] = bucket_tok[e * T_TOK + slot];
                s_w[tid]   = bucket_w[e * T_TOK + slot];
            } else { s_tok[tid] = -1; s_w[tid] = 0.f; }
        }
        __syncthreads();

        // per-chunk gathered/global staging pointers
        const int rAL0 = ALb * 8 + crow, rAL1 = rAL0 + 8;
        const int rAH0 = AHb * 8 + crow, rAH1 = rAH0 + 8;
        const int tAL0 = s_tok[rAL0], tAL1 = s_tok[rAL1];
        const int tAH0 = s_tok[rAH0], tAH1 = s_tok[rAH1];
        const u16* gAL0 = xb + (size_t)(tAL0 >= 0 ? (tAL0 >> 2) : 0) * DH + gsw;
        const u16* gAL1 = xb + (size_t)(tAL1 >= 0 ? (tAL1 >> 2) : 0) * DH + gsw;
        const u16* gAH0 = xb + (size_t)(tAH0 >= 0 ? (tAH0 >> 2) : 0) * DH + gsw;
        const u16* gAH1 = xb + (size_t)(tAH1 >= 0 ? (tAH1 >> 2) : 0) * DH + gsw;
        const u16* wbe  = wbt + ((size_t)e << 20);
        const u16* gBL0 = wbe + (size_t)(n0 + BLb * 8 + crow) * DH + gsw;
        const u16* gBL1 = gBL0 + (size_t)8 * DH;
        const u16* gBH0 = wbe + (size_t)(n0 + BHb * 8 + crow) * DH + gsw;
        const u16* gBH1 = gBH0 + (size_t)8 * DH;

        f32x4 acc[8][4] = {};

        // prologue: tiles 0 and 1 fully staged (8 loads each per wave)
        #pragma unroll
        for (int kt = 0; kt < 2; kt++) {
            const int ko = kt * 64; const int p = kt;
            glds16(gAL0 + ko, &As[p][ALb * 512]); glds16(gAL1 + ko, &As[p][(ALb + 1) * 512]);
            glds16(gAH0 + ko, &As[p][AHb * 512]); glds16(gAH1 + ko, &As[p][(AHb + 1) * 512]);
            glds16(gBL0 + ko, &Bs[p][BLb * 512]); glds16(gBL1 + ko, &Bs[p][(BLb + 1) * 512]);
            glds16(gBH0 + ko, &Bs[p][BHb * 512]); glds16(gBH1 + ko, &Bs[p][(BHb + 1) * 512]);
        }
        asm volatile("s_waitcnt vmcnt(8)" ::: "memory");  // tile 0 resident (tile 1 in flight)
        SBAR();

        const int arow = (wr * 128 + fr) * 64;    // u16 base of this lane's A frag rows
        const int brow = (wc * 64  + fr) * 64;
        const int c0 = fq ^ swz;                  // k-half 0 column (u16)
        const int c1 = (32 + fq) ^ swz;           // k-half 1 column

        bf16x8 afL[4][2], afH[4][2], bfL[2][2], bfH[2][2];

        for (int kt = 0; kt < 16; ++kt) {
            const int p = kt & 1;
            const u16* Ap = &As[p][0];
            const u16* Bp = &Bs[p][0];

            // ---- P1: read afL(8)+bfL(4); stage A-H of kt+1 -> buf p^1; MFMA miL x njL ----
            #pragma unroll
            for (int mi = 0; mi < 4; mi++) {
                afL[mi][0] = *(const bf16x8*)&Ap[arow + mi * 1024 + c0];
                afL[mi][1] = *(const bf16x8*)&Ap[arow + mi * 1024 + c1];
            }
            #pragma unroll
            for (int nj = 0; nj < 2; nj++) {
                bfL[nj][0] = *(const bf16x8*)&Bp[brow + nj * 1024 + c0];
                bfL[nj][1] = *(const bf16x8*)&Bp[brow + nj * 1024 + c1];
            }
            if (kt >= 1 && kt <= 14) {             // A-H rows of p^1 died at end-P3 of kt-1
                const int ko = (kt + 1) * 64; const int q = (kt + 1) & 1;
                glds16(gAH0 + ko, &As[q][AHb * 512]);
                glds16(gAH1 + ko, &As[q][(AHb + 1) * 512]);
            }
            asm volatile("s_waitcnt lgkmcnt(8)" ::: "memory");   // 12-read phase hint (template)
            SBAR(); WAITLGKM0();
            __builtin_amdgcn_s_setprio(1);
            #pragma unroll
            for (int mi = 0; mi < 4; mi++)
                #pragma unroll
                for (int nj = 0; nj < 2; nj++) {
                    acc[mi][nj] = __builtin_amdgcn_mfma_f32_16x16x32_bf16(afL[mi][0], bfL[nj][0], acc[mi][nj], 0, 0, 0);
                    acc[mi][nj] = __builtin_amdgcn_mfma_f32_16x16x32_bf16(afL[mi][1], bfL[nj][1], acc[mi][nj], 0, 0, 0);
                }
            __builtin_amdgcn_s_setprio(0);
            SBAR();                                // A-L/B-L rows of buf p now dead

            // ---- P2: read bfH(4); stage A-L of kt+2 -> buf p; MFMA miL x njH ----
            #pragma unroll
            for (int nj = 0; nj < 2; nj++) {
                bfH[nj][0] = *(const bf16x8*)&Bp[brow + (nj + 2) * 1024 + c0];
                bfH[nj][1] = *(const bf16x8*)&Bp[brow + (nj + 2) * 1024 + c1];
            }
            if (kt <= 13) {
                const int ko = (kt + 2) * 64;
                glds16(gAL0 + ko, &As[p][ALb * 512]);
                glds16(gAL1 + ko, &As[p][(ALb + 1) * 512]);
            }
            SBAR(); WAITLGKM0();
            __builtin_amdgcn_s_setprio(1);
            #pragma unroll
            for (int mi = 0; mi < 4; mi++)
                #pragma unroll
                for (int nj = 0; nj < 2; nj++) {
                    acc[mi][nj + 2] = __builtin_amdgcn_mfma_f32_16x16x32_bf16(afL[mi][0], bfH[nj][0], acc[mi][nj + 2], 0, 0, 0);
                    acc[mi][nj + 2] = __builtin_amdgcn_mfma_f32_16x16x32_bf16(afL[mi][1], bfH[nj][1], acc[mi][nj + 2], 0, 0, 0);
                }
            __builtin_amdgcn_s_setprio(0);
            SBAR();                                // B-H rows of buf p now dead

            // ---- P3: read afH(8); stage B-L of kt+2 -> buf p; MFMA miH x njH ----
            #pragma unroll
            for (int mi = 0; mi < 4; mi++) {
                afH[mi][0] = *(const bf16x8*)&Ap[arow + (mi + 4) * 1024 + c0];
                afH[mi][1] = *(const bf16x8*)&Ap[arow + (mi + 4) * 1024 + c1];
            }
            if (kt <= 13) {
                const int ko = (kt + 2) * 64;
                glds16(gBL0 + ko, &Bs[p][BLb * 512]);
                glds16(gBL1 + ko, &Bs[p][(BLb + 1) * 512]);
            }
            SBAR(); WAITLGKM0();
            __builtin_amdgcn_s_setprio(1);
            #pragma unroll
            for (int mi = 0; mi < 4; mi++)
                #pragma unroll
                for (int nj = 0; nj < 2; nj++) {
                    acc[mi + 4][nj + 2] = __builtin_amdgcn_mfma_f32_16x16x32_bf16(afH[mi][0], bfH[nj][0], acc[mi + 4][nj + 2], 0, 0, 0);
                    acc[mi + 4][nj + 2] = __builtin_amdgcn_mfma_f32_16x16x32_bf16(afH[mi][1], bfH[nj][1], acc[mi + 4][nj + 2], 0, 0, 0);
                }
            __builtin_amdgcn_s_setprio(0);
            SBAR();                                // A-H rows of buf p now dead

            // ---- P4: stage B-H of kt+2 -> buf p; MFMA miH x njL (regs only); counted vmcnt ----
            if (kt <= 13) {
                const int ko = (kt + 2) * 64;
                glds16(gBH0 + ko, &Bs[p][BHb * 512]);
                glds16(gBH1 + ko, &Bs[p][(BHb + 1) * 512]);
            }
            __builtin_amdgcn_s_setprio(1);
            #pragma unroll
            for (int mi = 0; mi < 4; mi++)
                #pragma unroll
                for (int nj = 0; nj < 2; nj++) {
                    acc[mi + 4][nj] = __builtin_amdgcn_mfma_f32_16x16x32_bf16(afH[mi][0], bfL[nj][0], acc[mi + 4][nj], 0, 0, 0);
                    acc[mi + 4][nj] = __builtin_amdgcn_mfma_f32_16x16x32_bf16(afH[mi][1], bfL[nj][1], acc[mi + 4][nj], 0, 0, 0);
                }
            __builtin_amdgcn_s_setprio(0);
            // newer-than-(kt+1) loads = kt+2's A-L,B-L,B-H = 6 -> vmcnt(6) => tile kt+1 resident
            if (kt <= 13)      asm volatile("s_waitcnt vmcnt(6)" ::: "memory");
            else if (kt == 14) asm volatile("s_waitcnt vmcnt(0)" ::: "memory");  // drain for tile 15
            SBAR();
        }

        // C/D layout: col = lane&15, row = (lane>>4)*4 + r
        const int cl = lane & 15;
        const int rb = (lane >> 4) * 4;
        #pragma unroll
        for (int mi = 0; mi < 8; mi++) {
            #pragma unroll
            for (int r = 0; r < 4; r++) {
                const int srow = wr * 128 + mi * 16 + rb + r;
                const int tok = s_tok[srow];
                if (tok < 0) continue;
                const float w = s_w[srow];
                u16* yr = y + (size_t)tok * DH + (n0 + wc * 64 + cl);
                #pragma unroll
                for (int nj = 0; nj < 4; nj++)
                    yr[nj * 16] = f2b(acc[mi][nj][r] * w);
            }
        }
    }
}

// ---------------- combine: out[t] = sum_k y[t*4+k] + sum_k w_k*b[e_k]; block 0 does aux ----------------
__global__ __launch_bounds__(256) void combine_kernel(
    const u16* __restrict__ y, const int* __restrict__ tk_e, const float* __restrict__ tk_w,
    const float* __restrict__ bexp,
    const int* __restrict__ cnt, const float* __restrict__ probsum,
    float* __restrict__ out, float* __restrict__ out_aux)
{
    const int t = blockIdx.x;
    const int c = threadIdx.x * 4;
    if (t == 0 && threadIdx.x == 0) {
        float s = 0.f;
        for (int e = 0; e < NE; e++) s += (float)cnt[e] * probsum[e];
        out_aux[0] = s * (float)NE / ((float)T_TOK * (float)T_TOK);
    }
    float o0 = 0.f, o1 = 0.f, o2 = 0.f, o3 = 0.f;
    #pragma unroll
    for (int k = 0; k < TK; k++) {
        const int e   = tk_e[t * TK + k];
        const float w = tk_w[t * TK + k];
        const ushort4 yv = *(const ushort4*)(y + ((size_t)(t * TK + k)) * DH + c);
        const float4  bv = *(const float4*)(bexp + (size_t)e * DH + c);
        o0 += b2f(yv.x) + w * bv.x;
        o1 += b2f(yv.y) + w * bv.y;
        o2 += b2f(yv.z) + w * bv.z;
        o3 += b2f(yv.w) + w * bv.w;
    }
    float4 ov = {o0, o1, o2, o3};
    *(float4*)(out + (size_t)t * DH + c) = ov;
}

extern "C" void kernel_launch(void* const* d_in, const int* in_sizes, int n_in,
                              void* d_out, int out_size, void* d_ws, size_t ws_size,
                              hipStream_t stream)
{
    const float* x  = (const float*)d_in[0];
    const float* Wg = (const float*)d_in[1];
    const float* bg = (const float*)d_in[2];
    const float* W  = (const float*)d_in[3];
    const float* b  = (const float*)d_in[4];
    float* out = (float*)d_out;

    char* ws = (char*)d_ws;
    u16*   xb         = (u16*)(ws);                    // 16,777,216 B
    u16*   wbt        = (u16*)(ws + 16777216);         // 16,777,216 B
    u16*   y          = (u16*)(ws + 33554432);         // 67,108,864 B
    int*   bucket_tok = (int*)(ws + 100663296);        //    262,144 B
    float* bucket_w   = (float*)(ws + 100925440);      //    262,144 B
    int*   tk_e       = (int*)(ws + 101187584);        //    131,072 B
    float* tk_w       = (float*)(ws + 101318656);      //    131,072 B
    int*   cnt        = (int*)(ws + 101449728);        //         32 B
    float* probsum    = (float*)(ws + 101449760);      //         32 B

    hipMemsetAsync(cnt, 0, 64, stream);  // cnt + probsum

    cast_w_kernel<<<dim3(16, 16, NE), 256, 0, stream>>>(W, wbt);
    router_kernel<<<1024, 512, 0, stream>>>(x, Wg, bg, xb, bucket_tok, bucket_w, tk_e, tk_w, cnt, probsum);
    moe_gemm_kernel<<<dim3(256), 512, 0, stream>>>(xb, wbt, bucket_tok, bucket_w, cnt, y);
    combine_kernel<<<8192, 256, 0, stream>>>(y, tk_e, tk_w, b, cnt, probsum, out, out + (size_t)T_TOK * DH);
}